// Round 12
// baseline (190.078 us; speedup 1.0000x reference)
//
#include <hip/hip_runtime.h>
#include <math.h>

// LinearAttention: B=2, S=4096, D=1024, H=16, Dh=64
// Round 12: QKV -> k_gemm9<1,24> with XCD-supertiled block order (each XCD runs
// 3 sequential 8bx x 8by supertiles = 4MB L2-resident working set, the regime
// where the out-GEMM's blocks run 2x faster). Grid 1536 = exactly 2 rounds at
// 3 blocks/CU. k_prefix2 folded into k_attn3 prologue (one fewer launch).

#define EPSF 1e-8f

typedef unsigned short u16;
typedef unsigned int   u32;
typedef __attribute__((ext_vector_type(8))) short short8v;
typedef __attribute__((ext_vector_type(4))) float f32x4;

__device__ __forceinline__ float elu1(float x){ return x > 0.f ? x + 1.f : __expf(x); }
__device__ __forceinline__ u16 f2bf(float f){
    union{float f; u32 i;} c; c.f = f;
    u32 i = c.i + 0x7FFFu + ((c.i >> 16) & 1u);   // RNE
    return (u16)(i >> 16);
}
__device__ __forceinline__ float bf2f(u16 v){ union{u32 i; float f;} c; c.i = (u32)v << 16; return c.f; }
__device__ __forceinline__ float bflo(u32 v){ union{u32 i; float f;} c; c.i = v << 16; return c.f; }
__device__ __forceinline__ float bfhi(u32 v){ union{u32 i; float f;} c; c.i = v & 0xffff0000u; return c.f; }

__device__ __forceinline__ void gload16(const void* g, void* l){
    __builtin_amdgcn_global_load_lds((const __attribute__((address_space(1))) u32*)g,
                                     (__attribute__((address_space(3))) u32*)l, 16, 0, 0);
}

// ---------------- Kernel 0: cast fp32 -> bf16 ----------------
__global__ __launch_bounds__(256) void k_cast5(
    const float* __restrict__ x,  const float* __restrict__ wq,
    const float* __restrict__ wk, const float* __restrict__ wv,
    const float* __restrict__ wo,
    u16* __restrict__ xb, u16* __restrict__ wcat, u16* __restrict__ wob)
{
    size_t i8 = ((size_t)blockIdx.x * 256 + threadIdx.x) * 8;
    const float* s; u16* d; size_t off;
    if      (i8 <  8388608) { s = x;  d = xb;            off = i8; }
    else if (i8 <  9437184) { s = wq; d = wcat;          off = i8 - 8388608; }
    else if (i8 < 10485760) { s = wk; d = wcat + 1048576; off = i8 - 9437184; }
    else if (i8 < 11534336) { s = wv; d = wcat + 2097152; off = i8 - 10485760; }
    else                    { s = wo; d = wob;           off = i8 - 11534336; }
    float4 a = *(const float4*)&s[off];
    float4 b = *(const float4*)&s[off + 4];
    uint4 p;
    p.x = (u32)f2bf(a.x) | ((u32)f2bf(a.y) << 16);
    p.y = (u32)f2bf(a.z) | ((u32)f2bf(a.w) << 16);
    p.z = (u32)f2bf(b.x) | ((u32)f2bf(b.y) << 16);
    p.w = (u32)f2bf(b.z) | ((u32)f2bf(b.w) << 16);
    *(uint4*)&d[off] = p;
}

// ---------------- k_gemm9: GEMM-NT, 128x128 tile, 3-ring + counted vmcnt ----------------
// C[8192][...] = A[8192][1024] * W[NBY*128][1024]^T. BM=BN=128, BK=32.
// 4 waves (2m x 2n), wave tile 64x64, acc[4][4]. LDS ring: 3 x 16KB = 48KB ->
// 3 blocks/CU. Counted vmcnt(4) ring schedule (r6-proven, race audit there).
// XCD-SUPERTILED ordering: xcd = bid&7 owns bx in [xcd*8, xcd*8+8) x all by,
// processed as by-groups of 8: by = (s&7) + 8*(s>>6), bx = xcd*8 + ((s>>3)&7).
// -> per-XCD temporal working set = 8 A-panels (2MB) + 8 W-panels (2MB) = 4MB
// = one XCD L2 (the regime where out-GEMM blocks run 2x faster than r10 QKV).
// MODE 1: QKV fused (bf16 out + elu on Q,K; NBY=24, grid 1536 = 2 clean rounds).
// MODE 3: f32 out (NBY=8, grid 512 = 1 round).
template<int MODE, int NBY>
__global__ __launch_bounds__(256, 3) void k_gemm9(
    const u16* __restrict__ Ag, const u16* __restrict__ Wg, void* __restrict__ Cv)
{
    __shared__ __align__(16) char dsm[49152];
    const int bid = blockIdx.x;
    const int xcd = bid & 7;
    const int s   = bid >> 3;                       // 0 .. 8*NBY-1
    const int by  = (s & 7) + ((s >> 6) << 3);      // by-group of 8
    const int bx  = (xcd << 3) + ((s >> 3) & 7);    // XCD-local bx chunk
    const int m0  = bx * 128;
    const int n0  = by * 128;

    const int tid = threadIdx.x;
    const int l   = tid & 63;
    const int wid = tid >> 6;
    const int wm  = wid >> 1;
    const int wn  = wid & 1;
    const int li  = l & 15;
    const int kgi = l >> 4;

    const int ra0 = wm*64 + li;
    const int offA0 = ((ra0 >> 1) << 7) + (((((ra0 & 1) << 2) | kgi) ^ ((ra0 >> 1) & 7)) << 4);
    const int rb0 = wn*64 + li;
    const int offB0 = ((rb0 >> 1) << 7) + (((((rb0 & 1) << 2) | kgi) ^ ((rb0 >> 1) & 7)) << 4);

    const int sx   = (l & 7) ^ (l >> 3);
    const int rowb = 2*(wid*8 + (l >> 3)) + (sx >> 2);
    const int skg  = (sx & 3) * 8;
    const u16* srcA = Ag + (size_t)(m0 + rowb) * 1024 + skg;
    const u16* srcB = Wg + (size_t)(n0 + rowb) * 1024 + skg;

    f32x4 acc[4][4];
    #pragma unroll
    for (int m = 0; m < 4; ++m)
        #pragma unroll
        for (int n = 0; n < 4; ++n) acc[m][n] = (f32x4){0.f, 0.f, 0.f, 0.f};

    #define ST9(BUF, T) { \
        char* ab = dsm + (BUF)*16384; \
        char* bb = ab + 8192; \
        _Pragma("unroll") for (int j = 0; j < 2; ++j) \
            gload16(srcA + (size_t)j*65536 + (T)*32, ab + j*4096 + wid*1024); \
        _Pragma("unroll") for (int j = 0; j < 2; ++j) \
            gload16(srcB + (size_t)j*65536 + (T)*32, bb + j*4096 + wid*1024); }

    #define CP9(BUF) { \
        const char* Ab = dsm + (BUF)*16384; \
        const char* Bb = Ab + 8192; \
        short8v bfr[4]; \
        _Pragma("unroll") for (int n = 0; n < 4; ++n) bfr[n] = *(const short8v*)(Bb + offB0 + n*1024); \
        __builtin_amdgcn_s_setprio(1); \
        _Pragma("unroll") for (int m = 0; m < 4; ++m) { \
            short8v afr = *(const short8v*)(Ab + offA0 + m*1024); \
            _Pragma("unroll") for (int n = 0; n < 4; ++n) \
                acc[m][n] = __builtin_amdgcn_mfma_f32_16x16x32_bf16(afr, bfr[n], acc[m][n], 0, 0, 0); \
        } \
        __builtin_amdgcn_s_setprio(0); }

    #define STEP9(CUR, STB, TS) { \
        ST9(STB, TS); \
        CP9(CUR); \
        asm volatile("s_waitcnt vmcnt(4)"); \
        __builtin_amdgcn_s_barrier(); }

    ST9(0, 0); ST9(1, 1);
    asm volatile("s_waitcnt vmcnt(4)");
    __builtin_amdgcn_s_barrier();

    #pragma unroll 1
    for (int g = 0; g < 10; ++g) {
        const int t = g * 3;
        STEP9(0, 2, t + 2);
        STEP9(1, 0, t + 3);
        STEP9(2, 1, t + 4);
    }
    CP9(0);
    asm volatile("s_waitcnt vmcnt(0)");
    __builtin_amdgcn_s_barrier();
    CP9(1);
    #undef STEP9
    #undef CP9
    #undef ST9

    const int r0 = m0 + wm*64 + kgi*4;
    if (MODE == 1) {
        const int matrix = by >> 3;                 // 0:Q 1:K 2:V
        const bool do_elu = matrix < 2;
        u16* outp = (u16*)Cv + (size_t)matrix * 8388608;
        const int c0 = (by & 7)*128 + wn*64 + li;
        #pragma unroll
        for (int m = 0; m < 4; ++m)
            #pragma unroll
            for (int n = 0; n < 4; ++n)
                #pragma unroll
                for (int r = 0; r < 4; ++r) {
                    float v = acc[m][n][r];
                    if (do_elu) v = elu1(v);
                    outp[(size_t)(r0 + m*16 + r) * 1024 + c0 + n*16] = f2bf(v);
                }
    } else {
        float* outp = (float*)Cv;
        const int c0 = by*128 + wn*64 + li;
        #pragma unroll
        for (int m = 0; m < 4; ++m)
            #pragma unroll
            for (int n = 0; n < 4; ++n)
                #pragma unroll
                for (int r = 0; r < 4; ++r)
                    outp[(size_t)(r0 + m*16 + r) * 1024 + c0 + n*16] = acc[m][n][r];
    }
}

// ---------------- k_segsums: per-(bh,seg) KV-sum + K-sum via MFMA ----------------
// grid 512 = bh*16 + seg; block 256 (4 waves). Segment = 4 chunks of 64 rows.
// Writes RAW segment sums: SegKV[blk][e][d] bf16, SegKS[blk][d] f32.
#define LSTR 72
__global__ __launch_bounds__(256) void k_segsums(
    const u16* __restrict__ Kg, const u16* __restrict__ Vg,
    u16* __restrict__ SegKV, float* __restrict__ SegKS)
{
    const int tid = threadIdx.x;
    const int l = tid & 63;
    const int w = tid >> 6;
    const int bh  = blockIdx.x >> 4;
    const int seg = blockIdx.x & 15;
    const int row0 = (bh >> 4) * 4096 + seg * 256;
    const int col  = (bh & 15) * 64;
    const int li = l & 15;
    const int lg = l >> 4;

    __shared__ __align__(16) u16 Kt[64 * LSTR];
    __shared__ __align__(16) u16 Vt[64 * LSTR];
    __shared__ float ksPart[4][64];

    f32x4 Stacc[4];
    #pragma unroll
    for (int nd = 0; nd < 4; ++nd) Stacc[nd] = (f32x4){0.f, 0.f, 0.f, 0.f};
    float ksAcc = 0.f;

    for (int cc = 0; cc < 4; ++cc) {
        const int rc = row0 + cc * 64;
        #pragma unroll
        for (int r = 0; r < 2; ++r) {
            int idx = tid + r * 256;
            int i = idx >> 3, cg = (idx & 7) << 3;
            uint4 ku = *(const uint4*)&Kg[(size_t)(rc + i) * 1024 + col + cg];
            uint4 vu = *(const uint4*)&Vg[(size_t)(rc + i) * 1024 + col + cg];
            Kt[(cg+0)*LSTR + i] = (u16)(ku.x & 0xffff);
            Kt[(cg+1)*LSTR + i] = (u16)(ku.x >> 16);
            Kt[(cg+2)*LSTR + i] = (u16)(ku.y & 0xffff);
            Kt[(cg+3)*LSTR + i] = (u16)(ku.y >> 16);
            Kt[(cg+4)*LSTR + i] = (u16)(ku.z & 0xffff);
            Kt[(cg+5)*LSTR + i] = (u16)(ku.z >> 16);
            Kt[(cg+6)*LSTR + i] = (u16)(ku.w & 0xffff);
            Kt[(cg+7)*LSTR + i] = (u16)(ku.w >> 16);
            Vt[(cg+0)*LSTR + i] = (u16)(vu.x & 0xffff);
            Vt[(cg+1)*LSTR + i] = (u16)(vu.x >> 16);
            Vt[(cg+2)*LSTR + i] = (u16)(vu.y & 0xffff);
            Vt[(cg+3)*LSTR + i] = (u16)(vu.y >> 16);
            Vt[(cg+4)*LSTR + i] = (u16)(vu.z & 0xffff);
            Vt[(cg+5)*LSTR + i] = (u16)(vu.z >> 16);
            Vt[(cg+6)*LSTR + i] = (u16)(vu.w & 0xffff);
            Vt[(cg+7)*LSTR + i] = (u16)(vu.w >> 16);
        }
        __syncthreads();
        #pragma unroll
        for (int kc = 0; kc < 2; ++kc) {
            short8v av = *(const short8v*)&Vt[(w*16 + li) * LSTR + lg*8 + kc*32];
            #pragma unroll
            for (int nd = 0; nd < 4; ++nd) {
                short8v bk = *(const short8v*)&Kt[(nd*16 + li) * LSTR + lg*8 + kc*32];
                Stacc[nd] = __builtin_amdgcn_mfma_f32_16x16x32_bf16(av, bk, Stacc[nd], 0, 0, 0);
            }
        }
        {
            const int d = tid & 63, q = tid >> 6;
            float sx2 = 0.f;
            #pragma unroll
            for (int ii = 0; ii < 16; ++ii) sx2 += bf2f(Kt[d * LSTR + q*16 + ii]);
            ksPart[q][d] = sx2;
        }
        __syncthreads();
        if (tid < 64) ksAcc += ksPart[0][tid] + ksPart[1][tid] + ksPart[2][tid] + ksPart[3][tid];
        __syncthreads();
    }

    u16* out = &SegKV[(size_t)blockIdx.x * 4096];
    #pragma unroll
    for (int nd = 0; nd < 4; ++nd)
        #pragma unroll
        for (int r = 0; r < 4; ++r)
            out[(16*w + lg*4 + r) * 64 + nd*16 + li] = f2bf(Stacc[nd][r]);
    if (tid < 64) SegKS[(size_t)blockIdx.x * 64 + tid] = ksAcc;
}

// ---------------- k_attn3: fused 4-chunk segment scan (prefix folded in) ----------------
// grid 512 = bh*16 + seg; block 256 (4 waves). Prologue computes the exclusive
// prefix over segments < seg from RAW SegKV/SegKS (L2/L3-hot, <=60KB reads).
__global__ __launch_bounds__(256) void k_attn3(
    const u16* __restrict__ Qg, const u16* __restrict__ Kg, const u16* __restrict__ Vg,
    const u16* __restrict__ SegKV, const float* __restrict__ SegKS, u16* __restrict__ AO)
{
    const int tid = threadIdx.x;
    const int l = tid & 63;
    const int w = tid >> 6;
    const int bh  = blockIdx.x >> 4;
    const int seg = blockIdx.x & 15;
    const int row0 = (bh >> 4) * 4096 + seg * 256;
    const int col  = (bh & 15) * 64;
    const int li = l & 15;
    const int lg = l >> 4;
    const int i_row = w * 16 + li;

    __shared__ __align__(16) u16 Qs [64 * LSTR];
    __shared__ __align__(16) u16 Ks [64 * LSTR];
    __shared__ __align__(16) u16 Kt [64 * LSTR];
    __shared__ __align__(16) u16 Vt [64 * LSTR];
    __shared__ __align__(16) u16 Sts[64 * LSTR];
    __shared__ __align__(16) u16 Pl [64 * LSTR];
    __shared__ float ksum[64];
    __shared__ float ksPart[4][64];
    __shared__ float invdenL[64];

    // prologue: exclusive prefix over raw segment sums (seg may be 0)
    {
        const size_t kvbase = (size_t)bh * 16 * 4096;
        #pragma unroll 4
        for (int k = 0; k < 16; ++k) {
            int p = tid + k * 256;              // 0..4095 = e*64 + d
            float a = 0.f;
            for (int s2 = 0; s2 < seg; ++s2)
                a += bf2f(SegKV[kvbase + (size_t)s2 * 4096 + p]);
            Sts[(p >> 6) * LSTR + (p & 63)] = f2bf(a);
        }
        if (tid < 64) {
            const size_t ksbase = (size_t)bh * 16 * 64;
            float a = 0.f;
            for (int s2 = 0; s2 < seg; ++s2)
                a += SegKS[ksbase + (size_t)s2 * 64 + tid];
            ksum[tid] = a;
        }
    }
    __syncthreads();

    f32x4 Stacc[4];
    #pragma unroll
    for (int nd = 0; nd < 4; ++nd)
        #pragma unroll
        for (int r = 0; r < 4; ++r)
            Stacc[nd][r] = bf2f(Sts[(16*w + lg*4 + r) * LSTR + nd*16 + li]);

    for (int cc = 0; cc < 4; ++cc) {
        const int rc = row0 + cc * 64;
        #pragma unroll
        for (int r = 0; r < 2; ++r) {
            int idx = tid + r * 256;
            int i = idx >> 3, cg = (idx & 7) << 3;
            *(uint4*)&Qs[i*LSTR + cg] = *(const uint4*)&Qg[(size_t)(rc + i) * 1024 + col + cg];
            uint4 ku = *(const uint4*)&Kg[(size_t)(rc + i) * 1024 + col + cg];
            uint4 vu = *(const uint4*)&Vg[(size_t)(rc + i) * 1024 + col + cg];
            *(uint4*)&Ks[i*LSTR + cg] = ku;
            Kt[(cg+0)*LSTR + i] = (u16)(ku.x & 0xffff);
            Kt[(cg+1)*LSTR + i] = (u16)(ku.x >> 16);
            Kt[(cg+2)*LSTR + i] = (u16)(ku.y & 0xffff);
            Kt[(cg+3)*LSTR + i] = (u16)(ku.y >> 16);
            Kt[(cg+4)*LSTR + i] = (u16)(ku.z & 0xffff);
            Kt[(cg+5)*LSTR + i] = (u16)(ku.z >> 16);
            Kt[(cg+6)*LSTR + i] = (u16)(ku.w & 0xffff);
            Kt[(cg+7)*LSTR + i] = (u16)(ku.w >> 16);
            Vt[(cg+0)*LSTR + i] = (u16)(vu.x & 0xffff);
            Vt[(cg+1)*LSTR + i] = (u16)(vu.x >> 16);
            Vt[(cg+2)*LSTR + i] = (u16)(vu.y & 0xffff);
            Vt[(cg+3)*LSTR + i] = (u16)(vu.y >> 16);
            Vt[(cg+4)*LSTR + i] = (u16)(vu.z & 0xffff);
            Vt[(cg+5)*LSTR + i] = (u16)(vu.z >> 16);
            Vt[(cg+6)*LSTR + i] = (u16)(vu.w & 0xffff);
            Vt[(cg+7)*LSTR + i] = (u16)(vu.w >> 16);
        }
        __syncthreads();   // b1

        short8v bq[2];
        #pragma unroll
        for (int kc = 0; kc < 2; ++kc)
            bq[kc] = *(const short8v*)&Qs[i_row * LSTR + lg*8 + kc*32];

        float den = EPSF;
        #pragma unroll
        for (int mj = 0; mj < 4; ++mj) {
            f32x4 sacc = (f32x4){0.f, 0.f, 0.f, 0.f};
            #pragma unroll
            for (int kc = 0; kc < 2; ++kc) {
                short8v ak = *(const short8v*)&Ks[(mj*16 + li) * LSTR + lg*8 + kc*32];
                sacc = __builtin_amdgcn_mfma_f32_16x16x32_bf16(ak, bq[kc], sacc, 0, 0, 0);
            }
            const int jbase = mj*16 + lg*4;
            float pv[4];
            #pragma unroll
            for (int r = 0; r < 4; ++r) {
                float v = sacc[r];
                v = (jbase + r <= i_row) ? v : 0.f;
                den += v;
                pv[r] = v;
            }
            u32 lo = (u32)f2bf(pv[0]) | ((u32)f2bf(pv[1]) << 16);
            u32 hi = (u32)f2bf(pv[2]) | ((u32)f2bf(pv[3]) << 16);
            *(uint2*)&Pl[i_row * LSTR + jbase] = make_uint2(lo, hi);
        }
        {
            const int d0 = lg * 16;
            uint4 q1 = *(const uint4*)&Qs[i_row * LSTR + d0];
            uint4 q2 = *(const uint4*)&Qs[i_row * LSTR + d0 + 8];
            den += bflo(q1.x)*ksum[d0+0] + bfhi(q1.x)*ksum[d0+1]
                 + bflo(q1.y)*ksum[d0+2] + bfhi(q1.y)*ksum[d0+3]
                 + bflo(q1.z)*ksum[d0+4] + bfhi(q1.z)*ksum[d0+5]
                 + bflo(q1.w)*ksum[d0+6] + bfhi(q1.w)*ksum[d0+7]
                 + bflo(q2.x)*ksum[d0+8] + bfhi(q2.x)*ksum[d0+9]
                 + bflo(q2.y)*ksum[d0+10]+ bfhi(q2.y)*ksum[d0+11]
                 + bflo(q2.z)*ksum[d0+12]+ bfhi(q2.z)*ksum[d0+13]
                 + bflo(q2.w)*ksum[d0+14]+ bfhi(q2.w)*ksum[d0+15];
        }
        den += __shfl_xor(den, 16);
        den += __shfl_xor(den, 32);
        if (l < 16) invdenL[w*16 + l] = 1.f / den;

        if (cc < 3) {
            const int d = tid & 63, q = tid >> 6;
            float sx2 = 0.f;
            #pragma unroll
            for (int ii = 0; ii < 16; ++ii) sx2 += bf2f(Kt[d * LSTR + q*16 + ii]);
            ksPart[q][d] = sx2;
        }
        __syncthreads();   // b2

        f32x4 oacc[4];
        #pragma unroll
        for (int ne = 0; ne < 4; ++ne) oacc[ne] = (f32x4){0.f, 0.f, 0.f, 0.f};
        #pragma unroll
        for (int kc = 0; kc < 2; ++kc) {
            short8v ap = *(const short8v*)&Pl[i_row * LSTR + lg*8 + kc*32];
            short8v aq = bq[kc];
            #pragma unroll
            for (int ne = 0; ne < 4; ++ne) {
                short8v bv = *(const short8v*)&Vt [(ne*16 + li) * LSTR + lg*8 + kc*32];
                short8v bs = *(const short8v*)&Sts[(ne*16 + li) * LSTR + lg*8 + kc*32];
                oacc[ne] = __builtin_amdgcn_mfma_f32_16x16x32_bf16(ap, bv, oacc[ne], 0, 0, 0);
                oacc[ne] = __builtin_amdgcn_mfma_f32_16x16x32_bf16(aq, bs, oacc[ne], 0, 0, 0);
            }
        }
        if (cc < 3 && tid < 64)
            ksum[tid] += ksPart[0][tid] + ksPart[1][tid] + ksPart[2][tid] + ksPart[3][tid];

        if (cc < 3) {
            #pragma unroll
            for (int kc = 0; kc < 2; ++kc) {
                short8v av = *(const short8v*)&Vt[(w*16 + li) * LSTR + lg*8 + kc*32];
                #pragma unroll
                for (int nd = 0; nd < 4; ++nd) {
                    short8v bk = *(const short8v*)&Kt[(nd*16 + li) * LSTR + lg*8 + kc*32];
                    Stacc[nd] = __builtin_amdgcn_mfma_f32_16x16x32_bf16(av, bk, Stacc[nd], 0, 0, 0);
                }
            }
        }

        float inv[4];
        #pragma unroll
        for (int r = 0; r < 4; ++r) inv[r] = invdenL[w*16 + lg*4 + r];
        #pragma unroll
        for (int ne = 0; ne < 4; ++ne)
            #pragma unroll
            for (int r = 0; r < 4; ++r)
                Pl[(w*16 + lg*4 + r) * LSTR + ne*16 + li] = f2bf(oacc[ne][r] * inv[r]);
        #pragma unroll
        for (int p = 0; p < 2; ++p) {
            int idx2 = l + p * 64;
            int ro = w*16 + (idx2 >> 3), cg = (idx2 & 7) << 3;
            *(uint4*)&AO[(size_t)(rc + ro) * 1024 + col + cg] = *(const uint4*)&Pl[ro*LSTR + cg];
        }

        __syncthreads();   // b3
        if (cc < 3) {
            #pragma unroll
            for (int nd = 0; nd < 4; ++nd)
                #pragma unroll
                for (int r = 0; r < 4; ++r)
                    Sts[(16*w + lg*4 + r) * LSTR + nd*16 + li] = f2bf(Stacc[nd][r]);
            __syncthreads();   // b4
        }
    }
}

extern "C" void kernel_launch(void* const* d_in, const int* in_sizes, int n_in,
                              void* d_out, int out_size, void* d_ws, size_t ws_size,
                              hipStream_t stream)
{
    const float* x  = (const float*)d_in[0];
    const float* Wq = (const float*)d_in[1];
    const float* Wk = (const float*)d_in[2];
    const float* Wv = (const float*)d_in[3];
    const float* Wo = (const float*)d_in[4];
    float* out = (float*)d_out;

    char* w = (char*)d_ws;
    u16*   QKVb  = (u16*)(w);                       // 3 x 16777216 B = 50331648
    u16*   Qb    = QKVb;
    u16*   Kb    = QKVb + 8388608;
    u16*   Vb    = QKVb + 16777216;
    u16*   xb    = (u16*)(w + 50331648);            // 16777216 B (aliased AOb)
    u16*   AOb   = xb;
    u16*   Wcat  = (u16*)(w + 67108864);            //  6291456 B
    u16*   Wob   = (u16*)(w + 73400320);            //  2097152 B
    u16*   SegKV = (u16*)(w + 75497472);            //  4194304 B (raw seg sums)
    float* SegKS = (float*)(w + 79691776);          //   131072 B -> end 79822848

    k_cast5       <<<6144, 256, 0, stream>>>(x, Wq, Wk, Wv, Wo, xb, Wcat, Wob);
    k_gemm9<1,24> <<<1536, 256, 0, stream>>>(xb, Wcat, (void*)QKVb);
    k_segsums     <<<512,  256, 0, stream>>>(Kb, Vb, SegKV, SegKS);
    k_attn3       <<<512,  256, 0, stream>>>(Qb, Kb, Vb, SegKV, SegKS, AOb);
    k_gemm9<3,8>  <<<512,  256, 0, stream>>>(AOb, Wob, (void*)out);
}

// Round 13
// 137.793 us; speedup vs baseline: 1.3795x; 1.3795x over previous
//
#include <hip/hip_runtime.h>
#include <math.h>

// LinearAttention: B=2, S=4096, D=1024, H=16, Dh=64
// Round 13: r11 structure restored (separate k_prefix2; attn3 reads prefixed
// SegKV/SegKS — r12's folded prefix was a latency-bound serial chain, 79us).
// QKV keeps r12's XCD-supertiled k_gemm9<1,24> so this round's profile
// isolates the supertile A/B vs r11's k_gemm7 (62.8us).

#define EPSF 1e-8f

typedef unsigned short u16;
typedef unsigned int   u32;
typedef __attribute__((ext_vector_type(8))) short short8v;
typedef __attribute__((ext_vector_type(4))) float f32x4;

__device__ __forceinline__ float elu1(float x){ return x > 0.f ? x + 1.f : __expf(x); }
__device__ __forceinline__ u16 f2bf(float f){
    union{float f; u32 i;} c; c.f = f;
    u32 i = c.i + 0x7FFFu + ((c.i >> 16) & 1u);   // RNE
    return (u16)(i >> 16);
}
__device__ __forceinline__ float bf2f(u16 v){ union{u32 i; float f;} c; c.i = (u32)v << 16; return c.f; }
__device__ __forceinline__ float bflo(u32 v){ union{u32 i; float f;} c; c.i = v << 16; return c.f; }
__device__ __forceinline__ float bfhi(u32 v){ union{u32 i; float f;} c; c.i = v & 0xffff0000u; return c.f; }

__device__ __forceinline__ void gload16(const void* g, void* l){
    __builtin_amdgcn_global_load_lds((const __attribute__((address_space(1))) u32*)g,
                                     (__attribute__((address_space(3))) u32*)l, 16, 0, 0);
}

// ---------------- Kernel 0: cast fp32 -> bf16 ----------------
__global__ __launch_bounds__(256) void k_cast5(
    const float* __restrict__ x,  const float* __restrict__ wq,
    const float* __restrict__ wk, const float* __restrict__ wv,
    const float* __restrict__ wo,
    u16* __restrict__ xb, u16* __restrict__ wcat, u16* __restrict__ wob)
{
    size_t i8 = ((size_t)blockIdx.x * 256 + threadIdx.x) * 8;
    const float* s; u16* d; size_t off;
    if      (i8 <  8388608) { s = x;  d = xb;            off = i8; }
    else if (i8 <  9437184) { s = wq; d = wcat;          off = i8 - 8388608; }
    else if (i8 < 10485760) { s = wk; d = wcat + 1048576; off = i8 - 9437184; }
    else if (i8 < 11534336) { s = wv; d = wcat + 2097152; off = i8 - 10485760; }
    else                    { s = wo; d = wob;           off = i8 - 11534336; }
    float4 a = *(const float4*)&s[off];
    float4 b = *(const float4*)&s[off + 4];
    uint4 p;
    p.x = (u32)f2bf(a.x) | ((u32)f2bf(a.y) << 16);
    p.y = (u32)f2bf(a.z) | ((u32)f2bf(a.w) << 16);
    p.z = (u32)f2bf(b.x) | ((u32)f2bf(b.y) << 16);
    p.w = (u32)f2bf(b.z) | ((u32)f2bf(b.w) << 16);
    *(uint4*)&d[off] = p;
}

// ---------------- k_gemm9: GEMM-NT, 128x128 tile, 3-ring + counted vmcnt ----------------
// XCD-supertiled block order: xcd = bid&7; per-XCD working set = 8 A-panels +
// 8 W-panels = 4MB = one XCD L2. 3 blocks/CU (48KB LDS).
template<int MODE, int NBY>
__global__ __launch_bounds__(256, 3) void k_gemm9(
    const u16* __restrict__ Ag, const u16* __restrict__ Wg, void* __restrict__ Cv)
{
    __shared__ __align__(16) char dsm[49152];
    const int bid = blockIdx.x;
    const int xcd = bid & 7;
    const int s   = bid >> 3;                       // 0 .. 8*NBY-1
    const int by  = (s & 7) + ((s >> 6) << 3);
    const int bx  = (xcd << 3) + ((s >> 3) & 7);
    const int m0  = bx * 128;
    const int n0  = by * 128;

    const int tid = threadIdx.x;
    const int l   = tid & 63;
    const int wid = tid >> 6;
    const int wm  = wid >> 1;
    const int wn  = wid & 1;
    const int li  = l & 15;
    const int kgi = l >> 4;

    const int ra0 = wm*64 + li;
    const int offA0 = ((ra0 >> 1) << 7) + (((((ra0 & 1) << 2) | kgi) ^ ((ra0 >> 1) & 7)) << 4);
    const int rb0 = wn*64 + li;
    const int offB0 = ((rb0 >> 1) << 7) + (((((rb0 & 1) << 2) | kgi) ^ ((rb0 >> 1) & 7)) << 4);

    const int sx   = (l & 7) ^ (l >> 3);
    const int rowb = 2*(wid*8 + (l >> 3)) + (sx >> 2);
    const int skg  = (sx & 3) * 8;
    const u16* srcA = Ag + (size_t)(m0 + rowb) * 1024 + skg;
    const u16* srcB = Wg + (size_t)(n0 + rowb) * 1024 + skg;

    f32x4 acc[4][4];
    #pragma unroll
    for (int m = 0; m < 4; ++m)
        #pragma unroll
        for (int n = 0; n < 4; ++n) acc[m][n] = (f32x4){0.f, 0.f, 0.f, 0.f};

    #define ST9(BUF, T) { \
        char* ab = dsm + (BUF)*16384; \
        char* bb = ab + 8192; \
        _Pragma("unroll") for (int j = 0; j < 2; ++j) \
            gload16(srcA + (size_t)j*65536 + (T)*32, ab + j*4096 + wid*1024); \
        _Pragma("unroll") for (int j = 0; j < 2; ++j) \
            gload16(srcB + (size_t)j*65536 + (T)*32, bb + j*4096 + wid*1024); }

    #define CP9(BUF) { \
        const char* Ab = dsm + (BUF)*16384; \
        const char* Bb = Ab + 8192; \
        short8v bfr[4]; \
        _Pragma("unroll") for (int n = 0; n < 4; ++n) bfr[n] = *(const short8v*)(Bb + offB0 + n*1024); \
        __builtin_amdgcn_s_setprio(1); \
        _Pragma("unroll") for (int m = 0; m < 4; ++m) { \
            short8v afr = *(const short8v*)(Ab + offA0 + m*1024); \
            _Pragma("unroll") for (int n = 0; n < 4; ++n) \
                acc[m][n] = __builtin_amdgcn_mfma_f32_16x16x32_bf16(afr, bfr[n], acc[m][n], 0, 0, 0); \
        } \
        __builtin_amdgcn_s_setprio(0); }

    #define STEP9(CUR, STB, TS) { \
        ST9(STB, TS); \
        CP9(CUR); \
        asm volatile("s_waitcnt vmcnt(4)"); \
        __builtin_amdgcn_s_barrier(); }

    ST9(0, 0); ST9(1, 1);
    asm volatile("s_waitcnt vmcnt(4)");
    __builtin_amdgcn_s_barrier();

    #pragma unroll 1
    for (int g = 0; g < 10; ++g) {
        const int t = g * 3;
        STEP9(0, 2, t + 2);
        STEP9(1, 0, t + 3);
        STEP9(2, 1, t + 4);
    }
    CP9(0);
    asm volatile("s_waitcnt vmcnt(0)");
    __builtin_amdgcn_s_barrier();
    CP9(1);
    #undef STEP9
    #undef CP9
    #undef ST9

    const int r0 = m0 + wm*64 + kgi*4;
    if (MODE == 1) {
        const int matrix = by >> 3;                 // 0:Q 1:K 2:V
        const bool do_elu = matrix < 2;
        u16* outp = (u16*)Cv + (size_t)matrix * 8388608;
        const int c0 = (by & 7)*128 + wn*64 + li;
        #pragma unroll
        for (int m = 0; m < 4; ++m)
            #pragma unroll
            for (int n = 0; n < 4; ++n)
                #pragma unroll
                for (int r = 0; r < 4; ++r) {
                    float v = acc[m][n][r];
                    if (do_elu) v = elu1(v);
                    outp[(size_t)(r0 + m*16 + r) * 1024 + c0 + n*16] = f2bf(v);
                }
    } else {
        float* outp = (float*)Cv;
        const int c0 = by*128 + wn*64 + li;
        #pragma unroll
        for (int m = 0; m < 4; ++m)
            #pragma unroll
            for (int n = 0; n < 4; ++n)
                #pragma unroll
                for (int r = 0; r < 4; ++r)
                    outp[(size_t)(r0 + m*16 + r) * 1024 + c0 + n*16] = acc[m][n][r];
    }
}

// ---------------- k_segsums: per-(bh,seg) KV-sum + K-sum via MFMA ----------------
// grid 512 = bh*16 + seg; block 256. Writes RAW segment sums.
#define LSTR 72
__global__ __launch_bounds__(256) void k_segsums(
    const u16* __restrict__ Kg, const u16* __restrict__ Vg,
    u16* __restrict__ SegKV, float* __restrict__ SegKS)
{
    const int tid = threadIdx.x;
    const int l = tid & 63;
    const int w = tid >> 6;
    const int bh  = blockIdx.x >> 4;
    const int seg = blockIdx.x & 15;
    const int row0 = (bh >> 4) * 4096 + seg * 256;
    const int col  = (bh & 15) * 64;
    const int li = l & 15;
    const int lg = l >> 4;

    __shared__ __align__(16) u16 Kt[64 * LSTR];
    __shared__ __align__(16) u16 Vt[64 * LSTR];
    __shared__ float ksPart[4][64];

    f32x4 Stacc[4];
    #pragma unroll
    for (int nd = 0; nd < 4; ++nd) Stacc[nd] = (f32x4){0.f, 0.f, 0.f, 0.f};
    float ksAcc = 0.f;

    for (int cc = 0; cc < 4; ++cc) {
        const int rc = row0 + cc * 64;
        #pragma unroll
        for (int r = 0; r < 2; ++r) {
            int idx = tid + r * 256;
            int i = idx >> 3, cg = (idx & 7) << 3;
            uint4 ku = *(const uint4*)&Kg[(size_t)(rc + i) * 1024 + col + cg];
            uint4 vu = *(const uint4*)&Vg[(size_t)(rc + i) * 1024 + col + cg];
            Kt[(cg+0)*LSTR + i] = (u16)(ku.x & 0xffff);
            Kt[(cg+1)*LSTR + i] = (u16)(ku.x >> 16);
            Kt[(cg+2)*LSTR + i] = (u16)(ku.y & 0xffff);
            Kt[(cg+3)*LSTR + i] = (u16)(ku.y >> 16);
            Kt[(cg+4)*LSTR + i] = (u16)(ku.z & 0xffff);
            Kt[(cg+5)*LSTR + i] = (u16)(ku.z >> 16);
            Kt[(cg+6)*LSTR + i] = (u16)(ku.w & 0xffff);
            Kt[(cg+7)*LSTR + i] = (u16)(ku.w >> 16);
            Vt[(cg+0)*LSTR + i] = (u16)(vu.x & 0xffff);
            Vt[(cg+1)*LSTR + i] = (u16)(vu.x >> 16);
            Vt[(cg+2)*LSTR + i] = (u16)(vu.y & 0xffff);
            Vt[(cg+3)*LSTR + i] = (u16)(vu.y >> 16);
            Vt[(cg+4)*LSTR + i] = (u16)(vu.z & 0xffff);
            Vt[(cg+5)*LSTR + i] = (u16)(vu.z >> 16);
            Vt[(cg+6)*LSTR + i] = (u16)(vu.w & 0xffff);
            Vt[(cg+7)*LSTR + i] = (u16)(vu.w >> 16);
        }
        __syncthreads();
        #pragma unroll
        for (int kc = 0; kc < 2; ++kc) {
            short8v av = *(const short8v*)&Vt[(w*16 + li) * LSTR + lg*8 + kc*32];
            #pragma unroll
            for (int nd = 0; nd < 4; ++nd) {
                short8v bk = *(const short8v*)&Kt[(nd*16 + li) * LSTR + lg*8 + kc*32];
                Stacc[nd] = __builtin_amdgcn_mfma_f32_16x16x32_bf16(av, bk, Stacc[nd], 0, 0, 0);
            }
        }
        {
            const int d = tid & 63, q = tid >> 6;
            float sx2 = 0.f;
            #pragma unroll
            for (int ii = 0; ii < 16; ++ii) sx2 += bf2f(Kt[d * LSTR + q*16 + ii]);
            ksPart[q][d] = sx2;
        }
        __syncthreads();
        if (tid < 64) ksAcc += ksPart[0][tid] + ksPart[1][tid] + ksPart[2][tid] + ksPart[3][tid];
        __syncthreads();
    }

    u16* out = &SegKV[(size_t)blockIdx.x * 4096];
    #pragma unroll
    for (int nd = 0; nd < 4; ++nd)
        #pragma unroll
        for (int r = 0; r < 4; ++r)
            out[(16*w + lg*4 + r) * 64 + nd*16 + li] = f2bf(Stacc[nd][r]);
    if (tid < 64) SegKS[(size_t)blockIdx.x * 64 + tid] = ksAcc;
}

// ---------------- k_prefix2: exclusive prefix over 16 segments ----------------
__global__ __launch_bounds__(256) void k_prefix2(u16* __restrict__ SegKV, float* __restrict__ SegKS)
{
    if (blockIdx.x < 512) {
        const int bh = blockIdx.x >> 4;
        const int p  = ((blockIdx.x & 15) << 8) + threadIdx.x;   // 0..4095
        const size_t base = (size_t)bh * 16 * 4096 + p;
        float acc = 0.f;
        #pragma unroll
        for (int s = 0; s < 16; ++s) {
            float t = bf2f(SegKV[base + (size_t)s * 4096]);
            SegKV[base + (size_t)s * 4096] = f2bf(acc);
            acc += t;
        }
    } else {
        const int idx = (blockIdx.x - 512) * 256 + threadIdx.x;  // 0..2047
        const int bh = idx >> 6, d = idx & 63;
        const size_t base = (size_t)bh * 16 * 64 + d;
        float acc = 0.f;
        #pragma unroll
        for (int s = 0; s < 16; ++s) {
            float t = SegKS[base + (size_t)s * 64];
            SegKS[base + (size_t)s * 64] = acc;
            acc += t;
        }
    }
}

// ---------------- k_attn3: fused 4-chunk segment scan (prefixed inputs) ----------------
// grid 512 = bh*16 + seg; block 256 (4 waves).
__global__ __launch_bounds__(256) void k_attn3(
    const u16* __restrict__ Qg, const u16* __restrict__ Kg, const u16* __restrict__ Vg,
    const u16* __restrict__ SegKVp, const float* __restrict__ SegKSp, u16* __restrict__ AO)
{
    const int tid = threadIdx.x;
    const int l = tid & 63;
    const int w = tid >> 6;
    const int bh  = blockIdx.x >> 4;
    const int seg = blockIdx.x & 15;
    const int row0 = (bh >> 4) * 4096 + seg * 256;
    const int col  = (bh & 15) * 64;
    const int li = l & 15;
    const int lg = l >> 4;
    const int i_row = w * 16 + li;

    __shared__ __align__(16) u16 Qs [64 * LSTR];
    __shared__ __align__(16) u16 Ks [64 * LSTR];
    __shared__ __align__(16) u16 Kt [64 * LSTR];
    __shared__ __align__(16) u16 Vt [64 * LSTR];
    __shared__ __align__(16) u16 Sts[64 * LSTR];
    __shared__ __align__(16) u16 Pl [64 * LSTR];
    __shared__ float ksum[64];
    __shared__ float ksPart[4][64];
    __shared__ float invdenL[64];

    #pragma unroll
    for (int r = 0; r < 2; ++r) {
        int idx = tid + r * 256;
        int i = idx >> 3, cg = (idx & 7) << 3;
        *(uint4*)&Sts[i*LSTR + cg] = *(const uint4*)&SegKVp[(size_t)blockIdx.x * 4096 + i * 64 + cg];
    }
    if (tid < 64) ksum[tid] = SegKSp[(size_t)blockIdx.x * 64 + tid];
    __syncthreads();

    f32x4 Stacc[4];
    #pragma unroll
    for (int nd = 0; nd < 4; ++nd)
        #pragma unroll
        for (int r = 0; r < 4; ++r)
            Stacc[nd][r] = bf2f(Sts[(16*w + lg*4 + r) * LSTR + nd*16 + li]);

    for (int cc = 0; cc < 4; ++cc) {
        const int rc = row0 + cc * 64;
        #pragma unroll
        for (int r = 0; r < 2; ++r) {
            int idx = tid + r * 256;
            int i = idx >> 3, cg = (idx & 7) << 3;
            *(uint4*)&Qs[i*LSTR + cg] = *(const uint4*)&Qg[(size_t)(rc + i) * 1024 + col + cg];
            uint4 ku = *(const uint4*)&Kg[(size_t)(rc + i) * 1024 + col + cg];
            uint4 vu = *(const uint4*)&Vg[(size_t)(rc + i) * 1024 + col + cg];
            *(uint4*)&Ks[i*LSTR + cg] = ku;
            Kt[(cg+0)*LSTR + i] = (u16)(ku.x & 0xffff);
            Kt[(cg+1)*LSTR + i] = (u16)(ku.x >> 16);
            Kt[(cg+2)*LSTR + i] = (u16)(ku.y & 0xffff);
            Kt[(cg+3)*LSTR + i] = (u16)(ku.y >> 16);
            Kt[(cg+4)*LSTR + i] = (u16)(ku.z & 0xffff);
            Kt[(cg+5)*LSTR + i] = (u16)(ku.z >> 16);
            Kt[(cg+6)*LSTR + i] = (u16)(ku.w & 0xffff);
            Kt[(cg+7)*LSTR + i] = (u16)(ku.w >> 16);
            Vt[(cg+0)*LSTR + i] = (u16)(vu.x & 0xffff);
            Vt[(cg+1)*LSTR + i] = (u16)(vu.x >> 16);
            Vt[(cg+2)*LSTR + i] = (u16)(vu.y & 0xffff);
            Vt[(cg+3)*LSTR + i] = (u16)(vu.y >> 16);
            Vt[(cg+4)*LSTR + i] = (u16)(vu.z & 0xffff);
            Vt[(cg+5)*LSTR + i] = (u16)(vu.z >> 16);
            Vt[(cg+6)*LSTR + i] = (u16)(vu.w & 0xffff);
            Vt[(cg+7)*LSTR + i] = (u16)(vu.w >> 16);
        }
        __syncthreads();   // b1

        short8v bq[2];
        #pragma unroll
        for (int kc = 0; kc < 2; ++kc)
            bq[kc] = *(const short8v*)&Qs[i_row * LSTR + lg*8 + kc*32];

        float den = EPSF;
        #pragma unroll
        for (int mj = 0; mj < 4; ++mj) {
            f32x4 sacc = (f32x4){0.f, 0.f, 0.f, 0.f};
            #pragma unroll
            for (int kc = 0; kc < 2; ++kc) {
                short8v ak = *(const short8v*)&Ks[(mj*16 + li) * LSTR + lg*8 + kc*32];
                sacc = __builtin_amdgcn_mfma_f32_16x16x32_bf16(ak, bq[kc], sacc, 0, 0, 0);
            }
            const int jbase = mj*16 + lg*4;
            float pv[4];
            #pragma unroll
            for (int r = 0; r < 4; ++r) {
                float v = sacc[r];
                v = (jbase + r <= i_row) ? v : 0.f;
                den += v;
                pv[r] = v;
            }
            u32 lo = (u32)f2bf(pv[0]) | ((u32)f2bf(pv[1]) << 16);
            u32 hi = (u32)f2bf(pv[2]) | ((u32)f2bf(pv[3]) << 16);
            *(uint2*)&Pl[i_row * LSTR + jbase] = make_uint2(lo, hi);
        }
        {
            const int d0 = lg * 16;
            uint4 q1 = *(const uint4*)&Qs[i_row * LSTR + d0];
            uint4 q2 = *(const uint4*)&Qs[i_row * LSTR + d0 + 8];
            den += bflo(q1.x)*ksum[d0+0] + bfhi(q1.x)*ksum[d0+1]
                 + bflo(q1.y)*ksum[d0+2] + bfhi(q1.y)*ksum[d0+3]
                 + bflo(q1.z)*ksum[d0+4] + bfhi(q1.z)*ksum[d0+5]
                 + bflo(q1.w)*ksum[d0+6] + bfhi(q1.w)*ksum[d0+7]
                 + bflo(q2.x)*ksum[d0+8] + bfhi(q2.x)*ksum[d0+9]
                 + bflo(q2.y)*ksum[d0+10]+ bfhi(q2.y)*ksum[d0+11]
                 + bflo(q2.z)*ksum[d0+12]+ bfhi(q2.z)*ksum[d0+13]
                 + bflo(q2.w)*ksum[d0+14]+ bfhi(q2.w)*ksum[d0+15];
        }
        den += __shfl_xor(den, 16);
        den += __shfl_xor(den, 32);
        if (l < 16) invdenL[w*16 + l] = 1.f / den;

        if (cc < 3) {
            const int d = tid & 63, q = tid >> 6;
            float sx2 = 0.f;
            #pragma unroll
            for (int ii = 0; ii < 16; ++ii) sx2 += bf2f(Kt[d * LSTR + q*16 + ii]);
            ksPart[q][d] = sx2;
        }
        __syncthreads();   // b2

        f32x4 oacc[4];
        #pragma unroll
        for (int ne = 0; ne < 4; ++ne) oacc[ne] = (f32x4){0.f, 0.f, 0.f, 0.f};
        #pragma unroll
        for (int kc = 0; kc < 2; ++kc) {
            short8v ap = *(const short8v*)&Pl[i_row * LSTR + lg*8 + kc*32];
            short8v aq = bq[kc];
            #pragma unroll
            for (int ne = 0; ne < 4; ++ne) {
                short8v bv = *(const short8v*)&Vt [(ne*16 + li) * LSTR + lg*8 + kc*32];
                short8v bs = *(const short8v*)&Sts[(ne*16 + li) * LSTR + lg*8 + kc*32];
                oacc[ne] = __builtin_amdgcn_mfma_f32_16x16x32_bf16(ap, bv, oacc[ne], 0, 0, 0);
                oacc[ne] = __builtin_amdgcn_mfma_f32_16x16x32_bf16(aq, bs, oacc[ne], 0, 0, 0);
            }
        }
        if (cc < 3 && tid < 64)
            ksum[tid] += ksPart[0][tid] + ksPart[1][tid] + ksPart[2][tid] + ksPart[3][tid];

        if (cc < 3) {
            #pragma unroll
            for (int kc = 0; kc < 2; ++kc) {
                short8v av = *(const short8v*)&Vt[(w*16 + li) * LSTR + lg*8 + kc*32];
                #pragma unroll
                for (int nd = 0; nd < 4; ++nd) {
                    short8v bk = *(const short8v*)&Kt[(nd*16 + li) * LSTR + lg*8 + kc*32];
                    Stacc[nd] = __builtin_amdgcn_mfma_f32_16x16x32_bf16(av, bk, Stacc[nd], 0, 0, 0);
                }
            }
        }

        float inv[4];
        #pragma unroll
        for (int r = 0; r < 4; ++r) inv[r] = invdenL[w*16 + lg*4 + r];
        #pragma unroll
        for (int ne = 0; ne < 4; ++ne)
            #pragma unroll
            for (int r = 0; r < 4; ++r)
                Pl[(w*16 + lg*4 + r) * LSTR + ne*16 + li] = f2bf(oacc[ne][r] * inv[r]);
        #pragma unroll
        for (int p = 0; p < 2; ++p) {
            int idx2 = l + p * 64;
            int ro = w*16 + (idx2 >> 3), cg = (idx2 & 7) << 3;
            *(uint4*)&AO[(size_t)(rc + ro) * 1024 + col + cg] = *(const uint4*)&Pl[ro*LSTR + cg];
        }

        __syncthreads();   // b3
        if (cc < 3) {
            #pragma unroll
            for (int nd = 0; nd < 4; ++nd)
                #pragma unroll
                for (int r = 0; r < 4; ++r)
                    Sts[(16*w + lg*4 + r) * LSTR + nd*16 + li] = f2bf(Stacc[nd][r]);
            __syncthreads();   // b4
        }
    }
}

extern "C" void kernel_launch(void* const* d_in, const int* in_sizes, int n_in,
                              void* d_out, int out_size, void* d_ws, size_t ws_size,
                              hipStream_t stream)
{
    const float* x  = (const float*)d_in[0];
    const float* Wq = (const float*)d_in[1];
    const float* Wk = (const float*)d_in[2];
    const float* Wv = (const float*)d_in[3];
    const float* Wo = (const float*)d_in[4];
    float* out = (float*)d_out;

    char* w = (char*)d_ws;
    u16*   QKVb  = (u16*)(w);                       // 3 x 16777216 B = 50331648
    u16*   Qb    = QKVb;
    u16*   Kb    = QKVb + 8388608;
    u16*   Vb    = QKVb + 16777216;
    u16*   xb    = (u16*)(w + 50331648);            // 16777216 B (aliased AOb)
    u16*   AOb   = xb;
    u16*   Wcat  = (u16*)(w + 67108864);            //  6291456 B
    u16*   Wob   = (u16*)(w + 73400320);            //  2097152 B
    u16*   SegKV = (u16*)(w + 75497472);            //  4194304 B (prefix in-place)
    float* SegKS = (float*)(w + 79691776);          //   131072 B -> end 79822848

    k_cast5       <<<6144, 256, 0, stream>>>(x, Wq, Wk, Wv, Wo, xb, Wcat, Wob);
    k_gemm9<1,24> <<<1536, 256, 0, stream>>>(xb, Wcat, (void*)QKVb);
    k_segsums     <<<512,  256, 0, stream>>>(Kb, Vb, SegKV, SegKS);
    k_prefix2     <<<520,  256, 0, stream>>>(SegKV, SegKS);
    k_attn3       <<<512,  256, 0, stream>>>(Qb, Kb, Vb, SegKV, SegKS, AOb);
    k_gemm9<3,8>  <<<512,  256, 0, stream>>>(AOb, Wob, (void*)out);
}

// Round 14
// 131.500 us; speedup vs baseline: 1.4455x; 1.0478x over previous
//
#include <hip/hip_runtime.h>
#include <math.h>

// LinearAttention: B=2, S=4096, D=1024, H=16, Dh=64
// Round 14: QKV reverted to k_gemm7 (BM256xBN128 3-ring, 62.8us proven) with
// XCD-supertiled ordering added (4bx x 8by per XCD = 4MB L2-resident; verified
// on k_gemm9 to cut FETCH 143->57MB). Out-GEMM = k_gemm9<3,8>. Attention chain
// = r11/r13 segment scan (segsums -> prefix2 -> attn3).

#define EPSF 1e-8f

typedef unsigned short u16;
typedef unsigned int   u32;
typedef __attribute__((ext_vector_type(8))) short short8v;
typedef __attribute__((ext_vector_type(4))) float f32x4;

__device__ __forceinline__ float elu1(float x){ return x > 0.f ? x + 1.f : __expf(x); }
__device__ __forceinline__ u16 f2bf(float f){
    union{float f; u32 i;} c; c.f = f;
    u32 i = c.i + 0x7FFFu + ((c.i >> 16) & 1u);   // RNE
    return (u16)(i >> 16);
}
__device__ __forceinline__ float bf2f(u16 v){ union{u32 i; float f;} c; c.i = (u32)v << 16; return c.f; }
__device__ __forceinline__ float bflo(u32 v){ union{u32 i; float f;} c; c.i = v << 16; return c.f; }
__device__ __forceinline__ float bfhi(u32 v){ union{u32 i; float f;} c; c.i = v & 0xffff0000u; return c.f; }

__device__ __forceinline__ void gload16(const void* g, void* l){
    __builtin_amdgcn_global_load_lds((const __attribute__((address_space(1))) u32*)g,
                                     (__attribute__((address_space(3))) u32*)l, 16, 0, 0);
}

// ---------------- Kernel 0: cast fp32 -> bf16 ----------------
__global__ __launch_bounds__(256) void k_cast5(
    const float* __restrict__ x,  const float* __restrict__ wq,
    const float* __restrict__ wk, const float* __restrict__ wv,
    const float* __restrict__ wo,
    u16* __restrict__ xb, u16* __restrict__ wcat, u16* __restrict__ wob)
{
    size_t i8 = ((size_t)blockIdx.x * 256 + threadIdx.x) * 8;
    const float* s; u16* d; size_t off;
    if      (i8 <  8388608) { s = x;  d = xb;            off = i8; }
    else if (i8 <  9437184) { s = wq; d = wcat;          off = i8 - 8388608; }
    else if (i8 < 10485760) { s = wk; d = wcat + 1048576; off = i8 - 9437184; }
    else if (i8 < 11534336) { s = wv; d = wcat + 2097152; off = i8 - 10485760; }
    else                    { s = wo; d = wob;           off = i8 - 11534336; }
    float4 a = *(const float4*)&s[off];
    float4 b = *(const float4*)&s[off + 4];
    uint4 p;
    p.x = (u32)f2bf(a.x) | ((u32)f2bf(a.y) << 16);
    p.y = (u32)f2bf(a.z) | ((u32)f2bf(a.w) << 16);
    p.z = (u32)f2bf(b.x) | ((u32)f2bf(b.y) << 16);
    p.w = (u32)f2bf(b.z) | ((u32)f2bf(b.w) << 16);
    *(uint4*)&d[off] = p;
}

// ---------------- k_gemm7: QKV GEMM-NT, BM256xBN128, 3-ring + vmcnt(6) ----------------
// XCD-supertiled: xcd = bid&7 owns bx in [xcd*4, xcd*4+4); supertile = 4bx x 8by
// -> 4 A-panels (2MB) + 8 W-panels (2MB) = 4MB = one XCD L2. Grid 768 = 8*96.
__global__ __launch_bounds__(256, 2) void k_gemm7(
    const u16* __restrict__ Ag, const u16* __restrict__ Wg, u16* __restrict__ C)
{
    __shared__ __align__(16) char dsm[73728];
    const int bid   = blockIdx.x;
    const int xcd   = bid & 7;
    const int s     = bid >> 3;          // 0..95
    const int inner = s & 31;
    const int super = s >> 5;            // 0..2
    const int by    = (inner & 7) + super * 8;   // 0..23
    const int bx    = (xcd << 2) + (inner >> 3); // 0..31
    const int m0    = bx * 256;
    const int n0    = by * 128;

    const int tid = threadIdx.x;
    const int l   = tid & 63;
    const int wid = tid >> 6;
    const int wm  = wid >> 1;
    const int wn  = wid & 1;
    const int li  = l & 15;
    const int kgi = l >> 4;

    const int ra0 = wm*128 + li;
    const int offA0 = (ra0 >> 1)*128 + (((((ra0 & 1) << 2) | kgi) ^ ((ra0 >> 1) & 7)) << 4);
    const int rb0 = wn*64 + li;
    const int offB0 = (rb0 >> 1)*128 + (((((rb0 & 1) << 2) | kgi) ^ ((rb0 >> 1) & 7)) << 4);

    const int sx   = (l & 7) ^ (l >> 3);
    const int rowb = 2*(wid*8 + (l >> 3)) + (sx >> 2);
    const int skg  = (sx & 3) * 8;
    const u16* srcA = Ag + (size_t)(m0 + rowb) * 1024 + skg;
    const u16* srcB = Wg + (size_t)(n0 + rowb) * 1024 + skg;

    f32x4 acc[8][4];
    #pragma unroll
    for (int m = 0; m < 8; ++m)
        #pragma unroll
        for (int n = 0; n < 4; ++n) acc[m][n] = (f32x4){0.f, 0.f, 0.f, 0.f};

    #define ST7(BUF, T) { \
        char* ab = dsm + (BUF)*24576; \
        char* bb = ab + 16384; \
        _Pragma("unroll") for (int j = 0; j < 4; ++j) \
            gload16(srcA + (size_t)j*65536 + (T)*32, ab + j*4096 + wid*1024); \
        _Pragma("unroll") for (int j = 0; j < 2; ++j) \
            gload16(srcB + (size_t)j*65536 + (T)*32, bb + j*4096 + wid*1024); }

    #define CP7(BUF) { \
        const char* Ab = dsm + (BUF)*24576; \
        const char* Bb = Ab + 16384; \
        short8v bfr[4]; \
        _Pragma("unroll") for (int n = 0; n < 4; ++n) bfr[n] = *(const short8v*)(Bb + offB0 + n*1024); \
        __builtin_amdgcn_s_setprio(1); \
        _Pragma("unroll") for (int m = 0; m < 8; ++m) { \
            short8v afr = *(const short8v*)(Ab + offA0 + m*1024); \
            _Pragma("unroll") for (int n = 0; n < 4; ++n) \
                acc[m][n] = __builtin_amdgcn_mfma_f32_16x16x32_bf16(afr, bfr[n], acc[m][n], 0, 0, 0); \
        } \
        __builtin_amdgcn_s_setprio(0); }

    #define STEP7(CUR, STB, TS) { \
        ST7(STB, TS); \
        CP7(CUR); \
        asm volatile("s_waitcnt vmcnt(6)"); \
        __builtin_amdgcn_s_barrier(); }

    ST7(0, 0); ST7(1, 1);
    asm volatile("s_waitcnt vmcnt(6)");
    __builtin_amdgcn_s_barrier();

    #pragma unroll 1
    for (int g = 0; g < 10; ++g) {
        const int t = g * 3;
        STEP7(0, 2, t + 2);
        STEP7(1, 0, t + 3);
        STEP7(2, 1, t + 4);
    }
    CP7(0);
    asm volatile("s_waitcnt vmcnt(0)");
    __builtin_amdgcn_s_barrier();
    CP7(1);
    #undef STEP7
    #undef CP7
    #undef ST7

    // epilogue. C/D layout: col = lane&15, row = (lane>>4)*4 + reg
    const int matrix = by >> 3;                 // 0:Q 1:K 2:V
    const bool do_elu = matrix < 2;
    u16* outp = C + (size_t)matrix * 8388608;
    const int r0 = m0 + wm*128 + kgi*4;
    const int c0 = (by & 7)*128 + wn*64 + li;
    #pragma unroll
    for (int m = 0; m < 8; ++m)
        #pragma unroll
        for (int n = 0; n < 4; ++n)
            #pragma unroll
            for (int r = 0; r < 4; ++r) {
                float v = acc[m][n][r];
                if (do_elu) v = elu1(v);
                outp[(size_t)(r0 + m*16 + r) * 1024 + c0 + n*16] = f2bf(v);
            }
}

// ---------------- k_gemm9 (out GEMM): 128x128, 3-ring + vmcnt(4), supertiled ----------------
__global__ __launch_bounds__(256, 3) void k_gemm9o(
    const u16* __restrict__ Ag, const u16* __restrict__ Wg, float* __restrict__ Cv)
{
    __shared__ __align__(16) char dsm[49152];
    const int bid = blockIdx.x;
    const int xcd = bid & 7;
    const int s   = bid >> 3;                       // 0..63
    const int by  = s & 7;
    const int bx  = (xcd << 3) + ((s >> 3) & 7);
    const int m0  = bx * 128;
    const int n0  = by * 128;

    const int tid = threadIdx.x;
    const int l   = tid & 63;
    const int wid = tid >> 6;
    const int wm  = wid >> 1;
    const int wn  = wid & 1;
    const int li  = l & 15;
    const int kgi = l >> 4;

    const int ra0 = wm*64 + li;
    const int offA0 = ((ra0 >> 1) << 7) + (((((ra0 & 1) << 2) | kgi) ^ ((ra0 >> 1) & 7)) << 4);
    const int rb0 = wn*64 + li;
    const int offB0 = ((rb0 >> 1) << 7) + (((((rb0 & 1) << 2) | kgi) ^ ((rb0 >> 1) & 7)) << 4);

    const int sx   = (l & 7) ^ (l >> 3);
    const int rowb = 2*(wid*8 + (l >> 3)) + (sx >> 2);
    const int skg  = (sx & 3) * 8;
    const u16* srcA = Ag + (size_t)(m0 + rowb) * 1024 + skg;
    const u16* srcB = Wg + (size_t)(n0 + rowb) * 1024 + skg;

    f32x4 acc[4][4];
    #pragma unroll
    for (int m = 0; m < 4; ++m)
        #pragma unroll
        for (int n = 0; n < 4; ++n) acc[m][n] = (f32x4){0.f, 0.f, 0.f, 0.f};

    #define ST9(BUF, T) { \
        char* ab = dsm + (BUF)*16384; \
        char* bb = ab + 8192; \
        _Pragma("unroll") for (int j = 0; j < 2; ++j) \
            gload16(srcA + (size_t)j*65536 + (T)*32, ab + j*4096 + wid*1024); \
        _Pragma("unroll") for (int j = 0; j < 2; ++j) \
            gload16(srcB + (size_t)j*65536 + (T)*32, bb + j*4096 + wid*1024); }

    #define CP9(BUF) { \
        const char* Ab = dsm + (BUF)*16384; \
        const char* Bb = Ab + 8192; \
        short8v bfr[4]; \
        _Pragma("unroll") for (int n = 0; n < 4; ++n) bfr[n] = *(const short8v*)(Bb + offB0 + n*1024); \
        __builtin_amdgcn_s_setprio(1); \
        _Pragma("unroll") for (int m = 0; m < 4; ++m) { \
            short8v afr = *(const short8v*)(Ab + offA0 + m*1024); \
            _Pragma("unroll") for (int n = 0; n < 4; ++n) \
                acc[m][n] = __builtin_amdgcn_mfma_f32_16x16x32_bf16(afr, bfr[n], acc[m][n], 0, 0, 0); \
        } \
        __builtin_amdgcn_s_setprio(0); }

    #define STEP9(CUR, STB, TS) { \
        ST9(STB, TS); \
        CP9(CUR); \
        asm volatile("s_waitcnt vmcnt(4)"); \
        __builtin_amdgcn_s_barrier(); }

    ST9(0, 0); ST9(1, 1);
    asm volatile("s_waitcnt vmcnt(4)");
    __builtin_amdgcn_s_barrier();

    #pragma unroll 1
    for (int g = 0; g < 10; ++g) {
        const int t = g * 3;
        STEP9(0, 2, t + 2);
        STEP9(1, 0, t + 3);
        STEP9(2, 1, t + 4);
    }
    CP9(0);
    asm volatile("s_waitcnt vmcnt(0)");
    __builtin_amdgcn_s_barrier();
    CP9(1);
    #undef STEP9
    #undef CP9
    #undef ST9

    const int r0 = m0 + wm*64 + kgi*4;
    const int c0 = by*128 + wn*64 + li;
    #pragma unroll
    for (int m = 0; m < 4; ++m)
        #pragma unroll
        for (int n = 0; n < 4; ++n)
            #pragma unroll
            for (int r = 0; r < 4; ++r)
                Cv[(size_t)(r0 + m*16 + r) * 1024 + c0 + n*16] = acc[m][n][r];
}

// ---------------- k_segsums: per-(bh,seg) KV-sum + K-sum via MFMA ----------------
#define LSTR 72
__global__ __launch_bounds__(256) void k_segsums(
    const u16* __restrict__ Kg, const u16* __restrict__ Vg,
    u16* __restrict__ SegKV, float* __restrict__ SegKS)
{
    const int tid = threadIdx.x;
    const int l = tid & 63;
    const int w = tid >> 6;
    const int bh  = blockIdx.x >> 4;
    const int seg = blockIdx.x & 15;
    const int row0 = (bh >> 4) * 4096 + seg * 256;
    const int col  = (bh & 15) * 64;
    const int li = l & 15;
    const int lg = l >> 4;

    __shared__ __align__(16) u16 Kt[64 * LSTR];
    __shared__ __align__(16) u16 Vt[64 * LSTR];
    __shared__ float ksPart[4][64];

    f32x4 Stacc[4];
    #pragma unroll
    for (int nd = 0; nd < 4; ++nd) Stacc[nd] = (f32x4){0.f, 0.f, 0.f, 0.f};
    float ksAcc = 0.f;

    for (int cc = 0; cc < 4; ++cc) {
        const int rc = row0 + cc * 64;
        #pragma unroll
        for (int r = 0; r < 2; ++r) {
            int idx = tid + r * 256;
            int i = idx >> 3, cg = (idx & 7) << 3;
            uint4 ku = *(const uint4*)&Kg[(size_t)(rc + i) * 1024 + col + cg];
            uint4 vu = *(const uint4*)&Vg[(size_t)(rc + i) * 1024 + col + cg];
            Kt[(cg+0)*LSTR + i] = (u16)(ku.x & 0xffff);
            Kt[(cg+1)*LSTR + i] = (u16)(ku.x >> 16);
            Kt[(cg+2)*LSTR + i] = (u16)(ku.y & 0xffff);
            Kt[(cg+3)*LSTR + i] = (u16)(ku.y >> 16);
            Kt[(cg+4)*LSTR + i] = (u16)(ku.z & 0xffff);
            Kt[(cg+5)*LSTR + i] = (u16)(ku.z >> 16);
            Kt[(cg+6)*LSTR + i] = (u16)(ku.w & 0xffff);
            Kt[(cg+7)*LSTR + i] = (u16)(ku.w >> 16);
            Vt[(cg+0)*LSTR + i] = (u16)(vu.x & 0xffff);
            Vt[(cg+1)*LSTR + i] = (u16)(vu.x >> 16);
            Vt[(cg+2)*LSTR + i] = (u16)(vu.y & 0xffff);
            Vt[(cg+3)*LSTR + i] = (u16)(vu.y >> 16);
            Vt[(cg+4)*LSTR + i] = (u16)(vu.z & 0xffff);
            Vt[(cg+5)*LSTR + i] = (u16)(vu.z >> 16);
            Vt[(cg+6)*LSTR + i] = (u16)(vu.w & 0xffff);
            Vt[(cg+7)*LSTR + i] = (u16)(vu.w >> 16);
        }
        __syncthreads();
        #pragma unroll
        for (int kc = 0; kc < 2; ++kc) {
            short8v av = *(const short8v*)&Vt[(w*16 + li) * LSTR + lg*8 + kc*32];
            #pragma unroll
            for (int nd = 0; nd < 4; ++nd) {
                short8v bk = *(const short8v*)&Kt[(nd*16 + li) * LSTR + lg*8 + kc*32];
                Stacc[nd] = __builtin_amdgcn_mfma_f32_16x16x32_bf16(av, bk, Stacc[nd], 0, 0, 0);
            }
        }
        {
            const int d = tid & 63, q = tid >> 6;
            float sx2 = 0.f;
            #pragma unroll
            for (int ii = 0; ii < 16; ++ii) sx2 += bf2f(Kt[d * LSTR + q*16 + ii]);
            ksPart[q][d] = sx2;
        }
        __syncthreads();
        if (tid < 64) ksAcc += ksPart[0][tid] + ksPart[1][tid] + ksPart[2][tid] + ksPart[3][tid];
        __syncthreads();
    }

    u16* out = &SegKV[(size_t)blockIdx.x * 4096];
    #pragma unroll
    for (int nd = 0; nd < 4; ++nd)
        #pragma unroll
        for (int r = 0; r < 4; ++r)
            out[(16*w + lg*4 + r) * 64 + nd*16 + li] = f2bf(Stacc[nd][r]);
    if (tid < 64) SegKS[(size_t)blockIdx.x * 64 + tid] = ksAcc;
}

// ---------------- k_prefix2: exclusive prefix over 16 segments ----------------
__global__ __launch_bounds__(256) void k_prefix2(u16* __restrict__ SegKV, float* __restrict__ SegKS)
{
    if (blockIdx.x < 512) {
        const int bh = blockIdx.x >> 4;
        const int p  = ((blockIdx.x & 15) << 8) + threadIdx.x;
        const size_t base = (size_t)bh * 16 * 4096 + p;
        float acc = 0.f;
        #pragma unroll
        for (int s = 0; s < 16; ++s) {
            float t = bf2f(SegKV[base + (size_t)s * 4096]);
            SegKV[base + (size_t)s * 4096] = f2bf(acc);
            acc += t;
        }
    } else {
        const int idx = (blockIdx.x - 512) * 256 + threadIdx.x;
        const int bh = idx >> 6, d = idx & 63;
        const size_t base = (size_t)bh * 16 * 64 + d;
        float acc = 0.f;
        #pragma unroll
        for (int s = 0; s < 16; ++s) {
            float t = SegKS[base + (size_t)s * 64];
            SegKS[base + (size_t)s * 64] = acc;
            acc += t;
        }
    }
}

// ---------------- k_attn3: fused 4-chunk segment scan (prefixed inputs) ----------------
__global__ __launch_bounds__(256) void k_attn3(
    const u16* __restrict__ Qg, const u16* __restrict__ Kg, const u16* __restrict__ Vg,
    const u16* __restrict__ SegKVp, const float* __restrict__ SegKSp, u16* __restrict__ AO)
{
    const int tid = threadIdx.x;
    const int l = tid & 63;
    const int w = tid >> 6;
    const int bh  = blockIdx.x >> 4;
    const int seg = blockIdx.x & 15;
    const int row0 = (bh >> 4) * 4096 + seg * 256;
    const int col  = (bh & 15) * 64;
    const int li = l & 15;
    const int lg = l >> 4;
    const int i_row = w * 16 + li;

    __shared__ __align__(16) u16 Qs [64 * LSTR];
    __shared__ __align__(16) u16 Ks [64 * LSTR];
    __shared__ __align__(16) u16 Kt [64 * LSTR];
    __shared__ __align__(16) u16 Vt [64 * LSTR];
    __shared__ __align__(16) u16 Sts[64 * LSTR];
    __shared__ __align__(16) u16 Pl [64 * LSTR];
    __shared__ float ksum[64];
    __shared__ float ksPart[4][64];
    __shared__ float invdenL[64];

    #pragma unroll
    for (int r = 0; r < 2; ++r) {
        int idx = tid + r * 256;
        int i = idx >> 3, cg = (idx & 7) << 3;
        *(uint4*)&Sts[i*LSTR + cg] = *(const uint4*)&SegKVp[(size_t)blockIdx.x * 4096 + i * 64 + cg];
    }
    if (tid < 64) ksum[tid] = SegKSp[(size_t)blockIdx.x * 64 + tid];
    __syncthreads();

    f32x4 Stacc[4];
    #pragma unroll
    for (int nd = 0; nd < 4; ++nd)
        #pragma unroll
        for (int r = 0; r < 4; ++r)
            Stacc[nd][r] = bf2f(Sts[(16*w + lg*4 + r) * LSTR + nd*16 + li]);

    for (int cc = 0; cc < 4; ++cc) {
        const int rc = row0 + cc * 64;
        #pragma unroll
        for (int r = 0; r < 2; ++r) {
            int idx = tid + r * 256;
            int i = idx >> 3, cg = (idx & 7) << 3;
            *(uint4*)&Qs[i*LSTR + cg] = *(const uint4*)&Qg[(size_t)(rc + i) * 1024 + col + cg];
            uint4 ku = *(const uint4*)&Kg[(size_t)(rc + i) * 1024 + col + cg];
            uint4 vu = *(const uint4*)&Vg[(size_t)(rc + i) * 1024 + col + cg];
            *(uint4*)&Ks[i*LSTR + cg] = ku;
            Kt[(cg+0)*LSTR + i] = (u16)(ku.x & 0xffff);
            Kt[(cg+1)*LSTR + i] = (u16)(ku.x >> 16);
            Kt[(cg+2)*LSTR + i] = (u16)(ku.y & 0xffff);
            Kt[(cg+3)*LSTR + i] = (u16)(ku.y >> 16);
            Kt[(cg+4)*LSTR + i] = (u16)(ku.z & 0xffff);
            Kt[(cg+5)*LSTR + i] = (u16)(ku.z >> 16);
            Kt[(cg+6)*LSTR + i] = (u16)(ku.w & 0xffff);
            Kt[(cg+7)*LSTR + i] = (u16)(ku.w >> 16);
            Vt[(cg+0)*LSTR + i] = (u16)(vu.x & 0xffff);
            Vt[(cg+1)*LSTR + i] = (u16)(vu.x >> 16);
            Vt[(cg+2)*LSTR + i] = (u16)(vu.y & 0xffff);
            Vt[(cg+3)*LSTR + i] = (u16)(vu.y >> 16);
            Vt[(cg+4)*LSTR + i] = (u16)(vu.z & 0xffff);
            Vt[(cg+5)*LSTR + i] = (u16)(vu.z >> 16);
            Vt[(cg+6)*LSTR + i] = (u16)(vu.w & 0xffff);
            Vt[(cg+7)*LSTR + i] = (u16)(vu.w >> 16);
        }
        __syncthreads();   // b1

        short8v bq[2];
        #pragma unroll
        for (int kc = 0; kc < 2; ++kc)
            bq[kc] = *(const short8v*)&Qs[i_row * LSTR + lg*8 + kc*32];

        float den = EPSF;
        #pragma unroll
        for (int mj = 0; mj < 4; ++mj) {
            f32x4 sacc = (f32x4){0.f, 0.f, 0.f, 0.f};
            #pragma unroll
            for (int kc = 0; kc < 2; ++kc) {
                short8v ak = *(const short8v*)&Ks[(mj*16 + li) * LSTR + lg*8 + kc*32];
                sacc = __builtin_amdgcn_mfma_f32_16x16x32_bf16(ak, bq[kc], sacc, 0, 0, 0);
            }
            const int jbase = mj*16 + lg*4;
            float pv[4];
            #pragma unroll
            for (int r = 0; r < 4; ++r) {
                float v = sacc[r];
                v = (jbase + r <= i_row) ? v : 0.f;
                den += v;
                pv[r] = v;
            }
            u32 lo = (u32)f2bf(pv[0]) | ((u32)f2bf(pv[1]) << 16);
            u32 hi = (u32)f2bf(pv[2]) | ((u32)f2bf(pv[3]) << 16);
            *(uint2*)&Pl[i_row * LSTR + jbase] = make_uint2(lo, hi);
        }
        {
            const int d0 = lg * 16;
            uint4 q1 = *(const uint4*)&Qs[i_row * LSTR + d0];
            uint4 q2 = *(const uint4*)&Qs[i_row * LSTR + d0 + 8];
            den += bflo(q1.x)*ksum[d0+0] + bfhi(q1.x)*ksum[d0+1]
                 + bflo(q1.y)*ksum[d0+2] + bfhi(q1.y)*ksum[d0+3]
                 + bflo(q1.z)*ksum[d0+4] + bfhi(q1.z)*ksum[d0+5]
                 + bflo(q1.w)*ksum[d0+6] + bfhi(q1.w)*ksum[d0+7]
                 + bflo(q2.x)*ksum[d0+8] + bfhi(q2.x)*ksum[d0+9]
                 + bflo(q2.y)*ksum[d0+10]+ bfhi(q2.y)*ksum[d0+11]
                 + bflo(q2.z)*ksum[d0+12]+ bfhi(q2.z)*ksum[d0+13]
                 + bflo(q2.w)*ksum[d0+14]+ bfhi(q2.w)*ksum[d0+15];
        }
        den += __shfl_xor(den, 16);
        den += __shfl_xor(den, 32);
        if (l < 16) invdenL[w*16 + l] = 1.f / den;

        if (cc < 3) {
            const int d = tid & 63, q = tid >> 6;
            float sx2 = 0.f;
            #pragma unroll
            for (int ii = 0; ii < 16; ++ii) sx2 += bf2f(Kt[d * LSTR + q*16 + ii]);
            ksPart[q][d] = sx2;
        }
        __syncthreads();   // b2

        f32x4 oacc[4];
        #pragma unroll
        for (int ne = 0; ne < 4; ++ne) oacc[ne] = (f32x4){0.f, 0.f, 0.f, 0.f};
        #pragma unroll
        for (int kc = 0; kc < 2; ++kc) {
            short8v ap = *(const short8v*)&Pl[i_row * LSTR + lg*8 + kc*32];
            short8v aq = bq[kc];
            #pragma unroll
            for (int ne = 0; ne < 4; ++ne) {
                short8v bv = *(const short8v*)&Vt [(ne*16 + li) * LSTR + lg*8 + kc*32];
                short8v bs = *(const short8v*)&Sts[(ne*16 + li) * LSTR + lg*8 + kc*32];
                oacc[ne] = __builtin_amdgcn_mfma_f32_16x16x32_bf16(ap, bv, oacc[ne], 0, 0, 0);
                oacc[ne] = __builtin_amdgcn_mfma_f32_16x16x32_bf16(aq, bs, oacc[ne], 0, 0, 0);
            }
        }
        if (cc < 3 && tid < 64)
            ksum[tid] += ksPart[0][tid] + ksPart[1][tid] + ksPart[2][tid] + ksPart[3][tid];

        if (cc < 3) {
            #pragma unroll
            for (int kc = 0; kc < 2; ++kc) {
                short8v av = *(const short8v*)&Vt[(w*16 + li) * LSTR + lg*8 + kc*32];
                #pragma unroll
                for (int nd = 0; nd < 4; ++nd) {
                    short8v bk = *(const short8v*)&Kt[(nd*16 + li) * LSTR + lg*8 + kc*32];
                    Stacc[nd] = __builtin_amdgcn_mfma_f32_16x16x32_bf16(av, bk, Stacc[nd], 0, 0, 0);
                }
            }
        }

        float inv[4];
        #pragma unroll
        for (int r = 0; r < 4; ++r) inv[r] = invdenL[w*16 + lg*4 + r];
        #pragma unroll
        for (int ne = 0; ne < 4; ++ne)
            #pragma unroll
            for (int r = 0; r < 4; ++r)
                Pl[(w*16 + lg*4 + r) * LSTR + ne*16 + li] = f2bf(oacc[ne][r] * inv[r]);
        #pragma unroll
        for (int p = 0; p < 2; ++p) {
            int idx2 = l + p * 64;
            int ro = w*16 + (idx2 >> 3), cg = (idx2 & 7) << 3;
            *(uint4*)&AO[(size_t)(rc + ro) * 1024 + col + cg] = *(const uint4*)&Pl[ro*LSTR + cg];
        }

        __syncthreads();   // b3
        if (cc < 3) {
            #pragma unroll
            for (int nd = 0; nd < 4; ++nd)
                #pragma unroll
                for (int r = 0; r < 4; ++r)
                    Sts[(16*w + lg*4 + r) * LSTR + nd*16 + li] = f2bf(Stacc[nd][r]);
            __syncthreads();   // b4
        }
    }
}

extern "C" void kernel_launch(void* const* d_in, const int* in_sizes, int n_in,
                              void* d_out, int out_size, void* d_ws, size_t ws_size,
                              hipStream_t stream)
{
    const float* x  = (const float*)d_in[0];
    const float* Wq = (const float*)d_in[1];
    const float* Wk = (const float*)d_in[2];
    const float* Wv = (const float*)d_in[3];
    const float* Wo = (const float*)d_in[4];
    float* out = (float*)d_out;

    char* w = (char*)d_ws;
    u16*   QKVb  = (u16*)(w);                       // 3 x 16777216 B = 50331648
    u16*   Qb    = QKVb;
    u16*   Kb    = QKVb + 8388608;
    u16*   Vb    = QKVb + 16777216;
    u16*   xb    = (u16*)(w + 50331648);            // 16777216 B (aliased AOb)
    u16*   AOb   = xb;
    u16*   Wcat  = (u16*)(w + 67108864);            //  6291456 B
    u16*   Wob   = (u16*)(w + 73400320);            //  2097152 B
    u16*   SegKV = (u16*)(w + 75497472);            //  4194304 B (prefix in-place)
    float* SegKS = (float*)(w + 79691776);          //   131072 B -> end 79822848

    k_cast5   <<<6144, 256, 0, stream>>>(x, Wq, Wk, Wv, Wo, xb, Wcat, Wob);
    k_gemm7   <<<768,  256, 0, stream>>>(xb, Wcat, QKVb);
    k_segsums <<<512,  256, 0, stream>>>(Kb, Vb, SegKV, SegKS);
    k_prefix2 <<<520,  256, 0, stream>>>(SegKV, SegKS);
    k_attn3   <<<512,  256, 0, stream>>>(Qb, Kb, Vb, SegKV, SegKS, AOb);
    k_gemm9o  <<<512,  256, 0, stream>>>(AOb, Wob, out);
}